// Round 6
// baseline (326.944 us; speedup 1.0000x reference)
//
#include <hip/hip_runtime.h>
#include <cstdint>
#include <cstddef>

typedef __bf16 bf16;
typedef __bf16 bf16x8 __attribute__((ext_vector_type(8)));
typedef __bf16 bf16x4 __attribute__((ext_vector_type(4)));
typedef float  f32x4  __attribute__((ext_vector_type(4)));

#define C_EPS 1e-5f
#define NC_ 64
#define NH_ 256
#define NW_ 256
#define HP_ (NH_*NW_)

// workspace layout (bytes)
#define OFF_W1   0ull
#define OFF_W2   73728ull
#define OFF_AFF  147456ull

// swizzled LDS byte offset for [pixel p][ci] bf16 tile (128 B per pixel row),
// 16-B-granule XOR swizzle: pixel stride 128 B == 32 banks -> must swizzle.
__device__ __forceinline__ int lds_off(int p, int cib) {
    return p * 128 + (((cib) ^ (p & 7)) << 4);
}

// ---------------------------------------------------------------------------
// pack weights into MFMA B-frag order + BN affine fold
// packed index u = (((tap*2+kb)*4+nb)*64 + lane)*8 + j
//   lane holds w[co = nb*16 + (lane&15)][ci = kb*32 + (lane>>4)*8 + j][tap]
__global__ void k_pack(const float* __restrict__ w1, const float* __restrict__ w2,
                       const float* __restrict__ b1, const float* __restrict__ g1,
                       const float* __restrict__ be1, const float* __restrict__ m1,
                       const float* __restrict__ v1,
                       const float* __restrict__ b2, const float* __restrict__ g2,
                       const float* __restrict__ be2, const float* __restrict__ m2,
                       const float* __restrict__ v2,
                       bf16* __restrict__ wp1, bf16* __restrict__ wp2,
                       float* __restrict__ aff)
{
    int idx = blockIdx.x * 256 + threadIdx.x;
    if (idx < 2 * 36864) {
        int conv = idx / 36864;
        int u = idx - conv * 36864;
        int j  = u & 7;
        int l  = (u >> 3) & 63;
        int nb = (u >> 9) & 3;
        int kb = (u >> 11) & 1;
        int t  = u >> 12;                  // 0..8
        int co = nb * 16 + (l & 15);
        int ci = kb * 32 + ((l >> 4) << 3) + j;
        const float* w = conv ? w2 : w1;
        float val = w[(co * 64 + ci) * 9 + t];
        (conv ? wp2 : wp1)[u] = (bf16)val;
    } else {
        int c = idx - 2 * 36864;
        if (c < 64) {
            float s = g1[c] / sqrtf(v1[c] + C_EPS);
            aff[c]      = s;
            aff[64 + c] = b1[c] * s + (be1[c] - m1[c] * s);
        } else if (c < 128) {
            int cc = c - 64;
            float s = g2[cc] / sqrtf(v2[cc] + C_EPS);
            aff[128 + cc] = s;
            aff[192 + cc] = b2[cc] * s + (be2[cc] - m2[cc] * s);
        }
    }
}

// ---------------------------------------------------------------------------
// Fully fused: stage x(20x20 halo) -> conv1+BN1+PReLU (18x18 h in LDS,
// overwrites x; h zeroed outside image = conv2 SAME padding) -> conv2+BN2
// + x + bilinear(Haar edge computed per-thread from GLOBAL f32 x in the
// epilogue; cache-hot, no LDS, no long register live-range) -> out.
// LDS: 51200 B (x tile, then h tile aliased) -> 3 blocks/CU.
__global__ __launch_bounds__(256, 3)
void k_fused(const float* __restrict__ x, const bf16* __restrict__ wp1,
             const bf16* __restrict__ wp2, const float* __restrict__ aff,
             const float* __restrict__ aprelu, float* __restrict__ out)
{
    __shared__ uint4 smem[3200];                 // 51200 B
    char* sx = reinterpret_cast<char*>(smem);    // x then h (aliased)
    const int t = threadIdx.x;

    // XCD-bijective swizzle (2048 blocks, 8 XCDs): each XCD owns one image
    const int bid = blockIdx.x;
    const int logical = (bid & 7) * 256 + (bid >> 3);
    const int x0 = (logical & 15) * 16;
    const int y0 = ((logical >> 4) & 15) * 16;
    const int bb = logical >> 8;
    const float* xb = x + (size_t)bb * NC_ * HP_;

    // ---- phase 1: stage x 20x20 halo (origin y0-2, x0-2) x 64 ci as bf16
    for (int i = 0; i < 25; ++i) {
        int item = i * 256 + t;                  // 6400 = 16 ci4 * 400 px
        int ci4 = item / 400;
        int p   = item - ci4 * 400;
        int r = p / 20, c = p - r * 20;
        int yy = y0 - 2 + r, xx = x0 - 2 + c;
        float v0 = 0.f, v1 = 0.f, v2 = 0.f, v3 = 0.f;
        if (yy >= 0 && yy < NH_ && xx >= 0 && xx < NW_) {
            const float* s = xb + (size_t)(ci4 * 4) * HP_ + yy * NW_ + xx;
            v0 = s[0]; v1 = s[HP_]; v2 = s[2 * HP_]; v3 = s[3 * HP_];
        }
        bf16x4 pk = { (bf16)v0, (bf16)v1, (bf16)v2, (bf16)v3 };
        *reinterpret_cast<bf16x4*>(sx + lds_off(p, ci4 >> 1) + ((ci4 & 1) << 3)) = pk;
    }
    __syncthreads();

    const int w = t >> 6, l = t & 63;
    const int l15 = l & 15, lg = l >> 4;

    // ---- phase 2: conv1 MFMAs -> 18x18 h in registers
    f32x4 acc1[6][4];
    #pragma unroll
    for (int j = 0; j < 6; ++j)
        #pragma unroll
        for (int cb = 0; cb < 4; ++cb) acc1[j][cb] = f32x4{0.f, 0.f, 0.f, 0.f};

    int prj[6], pcj[6];
    #pragma unroll
    for (int j = 0; j < 6; ++j) {
        int g = w + 4 * j;
        int p = g * 16 + l15; if (p > 323) p = 323;   // addr-safe clamp
        prj[j] = p / 18; pcj[j] = p - prj[j] * 18;
    }

    const bf16x8* wv1 = reinterpret_cast<const bf16x8*>(wp1);
    #pragma unroll
    for (int ky = 0; ky < 3; ++ky)
    #pragma unroll
    for (int kx = 0; kx < 3; ++kx)
    #pragma unroll
    for (int kb = 0; kb < 2; ++kb) {
        const int tap = ky * 3 + kx;
        bf16x8 wf[4];
        #pragma unroll
        for (int cb = 0; cb < 4; ++cb)
            wf[cb] = wv1[(((tap * 2 + kb) * 4 + cb) << 6) + l];
        #pragma unroll
        for (int j = 0; j < 6; ++j) {
            if (w + 4 * j > 20) continue;        // wave-uniform guard
            bf16x8 xf = *reinterpret_cast<const bf16x8*>(
                sx + lds_off((prj[j] + ky) * 20 + pcj[j] + kx, kb * 4 + lg));
            #pragma unroll
            for (int cb = 0; cb < 4; ++cb)
                acc1[j][cb] = __builtin_amdgcn_mfma_f32_16x16x32_bf16(wf[cb], xf, acc1[j][cb], 0, 0, 0);
        }
    }
    __syncthreads();                             // all x-LDS reads complete

    // ---- phase 3: BN1 + PReLU, write h over x region ([px 0..323][co]).
    // h pixels whose GLOBAL coords fall outside the image must be ZERO
    // (conv2's SAME padding pads h with zeros) — not conv1-of-padded-x.
    {
        const float apv = aprelu[0];
        #pragma unroll
        for (int j = 0; j < 6; ++j) {
            int g = w + 4 * j;
            if (g > 20) continue;
            int p = g * 16 + l15;
            if (p < 324) {
                const int hy = y0 - 1 + prj[j];
                const int hx = x0 - 1 + pcj[j];
                const bool valid = (hy >= 0) && (hy < NH_) && (hx >= 0) && (hx < NW_);
                #pragma unroll
                for (int cb = 0; cb < 4; ++cb) {
                    f32x4 al = *reinterpret_cast<const f32x4*>(aff + cb * 16 + lg * 4);
                    f32x4 be = *reinterpret_cast<const f32x4*>(aff + 64 + cb * 16 + lg * 4);
                    bf16x4 pk;
                    #pragma unroll
                    for (int r = 0; r < 4; ++r) {
                        float zv = acc1[j][cb][r] * al[r] + be[r];
                        float hv = zv > 0.f ? zv : apv * zv;
                        pk[r] = valid ? (bf16)hv : (bf16)0.f;
                    }
                    *reinterpret_cast<bf16x4*>(sx + lds_off(p, cb * 2 + (lg >> 1)) + ((lg & 1) << 3)) = pk;
                }
            }
        }
    }
    __syncthreads();                             // h tile visible to all

    // ---- phase 4: conv2 MFMAs (M = pixels, N = co)
    f32x4 acc2[4][4];
    #pragma unroll
    for (int a = 0; a < 4; ++a)
        #pragma unroll
        for (int b = 0; b < 4; ++b) acc2[a][b] = f32x4{0.f, 0.f, 0.f, 0.f};

    const bf16x8* wv2 = reinterpret_cast<const bf16x8*>(wp2);
    #pragma unroll
    for (int ky = 0; ky < 3; ++ky)
    #pragma unroll
    for (int kx = 0; kx < 3; ++kx)
    #pragma unroll
    for (int kb = 0; kb < 2; ++kb) {
        const int tap = ky * 3 + kx;
        bf16x8 wf[4];
        #pragma unroll
        for (int cb = 0; cb < 4; ++cb)
            wf[cb] = wv2[(((tap * 2 + kb) * 4 + cb) << 6) + l];
        #pragma unroll
        for (int pr = 0; pr < 4; ++pr) {
            int p = (w * 4 + pr + ky) * 18 + (l15 + kx);
            bf16x8 xf = *reinterpret_cast<const bf16x8*>(sx + lds_off(p, kb * 4 + lg));
            #pragma unroll
            for (int cb = 0; cb < 4; ++cb)
                acc2[pr][cb] = __builtin_amdgcn_mfma_f32_16x16x32_bf16(xf, wf[cb], acc2[pr][cb], 0, 0, 0);
        }
    }

    // ---- phase 5: BN2 + x + bilinear(Haar edge from GLOBAL f32 x), f32x4
    // stores (NCHW). Tap (gry,grx) clamped to [0,127]^2: clamped duplicate
    // taps reproduce jax's bilinear boundary semantics exactly. Tap source
    // lines are the block's own staged halo rows -> L2/L3-hot.
    #pragma unroll
    for (int cb = 0; cb < 4; ++cb) {
        const int co = cb * 16 + l15;
        const float* xs0 = x + ((size_t)bb * NC_ + co) * HP_;
        float et[4][4];
        #pragma unroll
        for (int r = 0; r < 4; ++r) {
            int gry = (y0 >> 1) - 1 + 2 * w + r;
            gry = gry < 0 ? 0 : (gry > 127 ? 127 : gry);
            const float* row0 = xs0 + (size_t)(2 * gry) * NW_;
            #pragma unroll
            for (int c = 0; c < 4; ++c) {
                int grx = (x0 >> 1) - 1 + 2 * lg + c;
                grx = grx < 0 ? 0 : (grx > 127 ? 127 : grx);
                float2 A = *reinterpret_cast<const float2*>(row0 + 2 * grx);
                float2 B = *reinterpret_cast<const float2*>(row0 + NW_ + 2 * grx);
                et[r][c] = (3.f * A.x - A.y - B.x - B.y) * 0.5f;
            }
        }
        const float al = aff[128 + co];
        const float bt = aff[192 + co];
        #pragma unroll
        for (int pr = 0; pr < 4; ++pr) {
            const int Y = y0 + w * 4 + pr;
            const int Xb = x0 + lg * 4;
            const int ry0 = (pr == 0) ? 0 : (pr == 3 ? 2 : 1);
            const float wyl = (pr & 1) ? 0.75f : 0.25f;
            f32x4 xq = *reinterpret_cast<const f32x4*>(xs0 + Y * NW_ + Xb);
            f32x4 o;
            #pragma unroll
            for (int rr = 0; rr < 4; ++rr) {
                const int rx0 = (rr == 0) ? 0 : (rr == 3 ? 2 : 1);
                const float wxl = (rr & 1) ? 0.75f : 0.25f;
                float e0 = wxl * et[ry0][rx0]     + (1.f - wxl) * et[ry0][rx0 + 1];
                float e1 = wxl * et[ry0 + 1][rx0] + (1.f - wxl) * et[ry0 + 1][rx0 + 1];
                float e  = wyl * e0 + (1.f - wyl) * e1;
                o[rr] = acc2[pr][cb][rr] * al + bt + xq[rr] + e;
            }
            float* os = out + ((size_t)bb * NC_ + co) * HP_ + Y * NW_ + Xb;
            *reinterpret_cast<f32x4*>(os) = o;
        }
    }
}

// ---------------------------------------------------------------------------
extern "C" void kernel_launch(void* const* d_in, const int* in_sizes, int n_in,
                              void* d_out, int out_size, void* d_ws, size_t ws_size,
                              hipStream_t stream)
{
    const float* x   = (const float*)d_in[0];
    const float* w1  = (const float*)d_in[1];
    const float* b1  = (const float*)d_in[2];
    const float* g1  = (const float*)d_in[3];
    const float* be1 = (const float*)d_in[4];
    const float* m1  = (const float*)d_in[5];
    const float* v1  = (const float*)d_in[6];
    const float* ap  = (const float*)d_in[7];
    const float* w2  = (const float*)d_in[8];
    const float* b2  = (const float*)d_in[9];
    const float* g2  = (const float*)d_in[10];
    const float* be2 = (const float*)d_in[11];
    const float* m2  = (const float*)d_in[12];
    const float* v2  = (const float*)d_in[13];

    char* ws = (char*)d_ws;
    bf16*  wp1  = (bf16*)(ws + OFF_W1);
    bf16*  wp2  = (bf16*)(ws + OFF_W2);
    float* aff  = (float*)(ws + OFF_AFF);
    float* outp = (float*)d_out;

    k_pack<<<dim3(290), dim3(256), 0, stream>>>(w1, w2, b1, g1, be1, m1, v1,
                                                b2, g2, be2, m2, v2, wp1, wp2, aff);
    k_fused<<<dim3(2048), dim3(256), 0, stream>>>(x, wp1, wp2, aff, ap, outp);
}

// Round 7
// 251.414 us; speedup vs baseline: 1.3004x; 1.3004x over previous
//
#include <hip/hip_runtime.h>
#include <cstdint>
#include <cstddef>

typedef __bf16 bf16;
typedef __bf16 bf16x8 __attribute__((ext_vector_type(8)));
typedef __bf16 bf16x4 __attribute__((ext_vector_type(4)));
typedef float  f32x4  __attribute__((ext_vector_type(4)));

#define C_EPS 1e-5f
#define NC_ 64
#define NH_ 256
#define NW_ 256
#define HP_ (NH_*NW_)

// workspace layout (bytes)
#define OFF_W1   0ull
#define OFF_W2   73728ull
#define OFF_AFF  147456ull

// swizzled LDS byte offset for [pixel p][ci] bf16 tile (128 B per pixel row),
// 16-B-granule XOR swizzle: pixel stride 128 B == 32 banks -> must swizzle.
__device__ __forceinline__ int lds_off(int p, int cib) {
    return p * 128 + (((cib) ^ (p & 7)) << 4);
}

// ---------------------------------------------------------------------------
// pack weights into MFMA B-frag order + BN affine fold
// packed index u = (((tap*2+kb)*4+nb)*64 + lane)*8 + j
//   lane holds w[co = nb*16 + (lane&15)][ci = kb*32 + (lane>>4)*8 + j][tap]
__global__ void k_pack(const float* __restrict__ w1, const float* __restrict__ w2,
                       const float* __restrict__ b1, const float* __restrict__ g1,
                       const float* __restrict__ be1, const float* __restrict__ m1,
                       const float* __restrict__ v1,
                       const float* __restrict__ b2, const float* __restrict__ g2,
                       const float* __restrict__ be2, const float* __restrict__ m2,
                       const float* __restrict__ v2,
                       bf16* __restrict__ wp1, bf16* __restrict__ wp2,
                       float* __restrict__ aff)
{
    int idx = blockIdx.x * 256 + threadIdx.x;
    if (idx < 2 * 36864) {
        int conv = idx / 36864;
        int u = idx - conv * 36864;
        int j  = u & 7;
        int l  = (u >> 3) & 63;
        int nb = (u >> 9) & 3;
        int kb = (u >> 11) & 1;
        int t  = u >> 12;                  // 0..8
        int co = nb * 16 + (l & 15);
        int ci = kb * 32 + ((l >> 4) << 3) + j;
        const float* w = conv ? w2 : w1;
        float val = w[(co * 64 + ci) * 9 + t];
        (conv ? wp2 : wp1)[u] = (bf16)val;
    } else {
        int c = idx - 2 * 36864;
        if (c < 64) {
            float s = g1[c] / sqrtf(v1[c] + C_EPS);
            aff[c]      = s;
            aff[64 + c] = b1[c] * s + (be1[c] - m1[c] * s);
        } else if (c < 128) {
            int cc = c - 64;
            float s = g2[cc] / sqrtf(v2[cc] + C_EPS);
            aff[128 + cc] = s;
            aff[192 + cc] = b2[cc] * s + (be2[cc] - m2[cc] * s);
        }
    }
}

// ---------------------------------------------------------------------------
// Fully fused: stage x(20x20 halo) -> conv1+BN1+PReLU (18x18 h in LDS,
// overwrites x; h zeroed outside image = conv2 SAME padding) -> conv2+BN2
// + x + bilinear(Haar edge computed per-thread from GLOBAL f32 x in the
// epilogue; cache-hot, transient registers only) -> out.
// LDS: 51200 B -> 3 blocks/CU (LDS-limited).
// __launch_bounds__(256,2): min-waves=3 made regalloc collapse to 84 VGPR and
// spill ~280 MB/launch to scratch (round-6 counters). (256,2) compiles the
// same conv structure to ~116 VGPR with zero spill; occupancy is then
// LDS-limited at 3 blocks/CU since VGPR<=170.
__global__ __launch_bounds__(256, 2)
void k_fused(const float* __restrict__ x, const bf16* __restrict__ wp1,
             const bf16* __restrict__ wp2, const float* __restrict__ aff,
             const float* __restrict__ aprelu, float* __restrict__ out)
{
    __shared__ uint4 smem[3200];                 // 51200 B
    char* sx = reinterpret_cast<char*>(smem);    // x then h (aliased)
    const int t = threadIdx.x;

    // XCD-bijective swizzle (2048 blocks, 8 XCDs): each XCD owns one image
    const int bid = blockIdx.x;
    const int logical = (bid & 7) * 256 + (bid >> 3);
    const int x0 = (logical & 15) * 16;
    const int y0 = ((logical >> 4) & 15) * 16;
    const int bb = logical >> 8;
    const float* xb = x + (size_t)bb * NC_ * HP_;

    // ---- phase 1: stage x 20x20 halo (origin y0-2, x0-2) x 64 ci as bf16
    for (int i = 0; i < 25; ++i) {
        int item = i * 256 + t;                  // 6400 = 16 ci4 * 400 px
        int ci4 = item / 400;
        int p   = item - ci4 * 400;
        int r = p / 20, c = p - r * 20;
        int yy = y0 - 2 + r, xx = x0 - 2 + c;
        float v0 = 0.f, v1 = 0.f, v2 = 0.f, v3 = 0.f;
        if (yy >= 0 && yy < NH_ && xx >= 0 && xx < NW_) {
            const float* s = xb + (size_t)(ci4 * 4) * HP_ + yy * NW_ + xx;
            v0 = s[0]; v1 = s[HP_]; v2 = s[2 * HP_]; v3 = s[3 * HP_];
        }
        bf16x4 pk = { (bf16)v0, (bf16)v1, (bf16)v2, (bf16)v3 };
        *reinterpret_cast<bf16x4*>(sx + lds_off(p, ci4 >> 1) + ((ci4 & 1) << 3)) = pk;
    }
    __syncthreads();

    const int w = t >> 6, l = t & 63;
    const int l15 = l & 15, lg = l >> 4;

    // ---- phase 2: conv1 MFMAs -> 18x18 h in registers
    f32x4 acc1[6][4];
    #pragma unroll
    for (int j = 0; j < 6; ++j)
        #pragma unroll
        for (int cb = 0; cb < 4; ++cb) acc1[j][cb] = f32x4{0.f, 0.f, 0.f, 0.f};

    int prj[6], pcj[6];
    #pragma unroll
    for (int j = 0; j < 6; ++j) {
        int g = w + 4 * j;
        int p = g * 16 + l15; if (p > 323) p = 323;   // addr-safe clamp
        prj[j] = p / 18; pcj[j] = p - prj[j] * 18;
    }

    const bf16x8* wv1 = reinterpret_cast<const bf16x8*>(wp1);
    #pragma unroll
    for (int ky = 0; ky < 3; ++ky)
    #pragma unroll
    for (int kx = 0; kx < 3; ++kx)
    #pragma unroll
    for (int kb = 0; kb < 2; ++kb) {
        const int tap = ky * 3 + kx;
        bf16x8 wf[4];
        #pragma unroll
        for (int cb = 0; cb < 4; ++cb)
            wf[cb] = wv1[(((tap * 2 + kb) * 4 + cb) << 6) + l];
        #pragma unroll
        for (int j = 0; j < 6; ++j) {
            if (w + 4 * j > 20) continue;        // wave-uniform guard
            bf16x8 xf = *reinterpret_cast<const bf16x8*>(
                sx + lds_off((prj[j] + ky) * 20 + pcj[j] + kx, kb * 4 + lg));
            #pragma unroll
            for (int cb = 0; cb < 4; ++cb)
                acc1[j][cb] = __builtin_amdgcn_mfma_f32_16x16x32_bf16(wf[cb], xf, acc1[j][cb], 0, 0, 0);
        }
    }
    __syncthreads();                             // all x-LDS reads complete

    // ---- phase 3: BN1 + PReLU, write h over x region ([px 0..323][co]).
    // h pixels whose GLOBAL coords fall outside the image must be ZERO
    // (conv2's SAME padding pads h with zeros) — not conv1-of-padded-x.
    {
        const float apv = aprelu[0];
        #pragma unroll
        for (int j = 0; j < 6; ++j) {
            int g = w + 4 * j;
            if (g > 20) continue;
            int p = g * 16 + l15;
            if (p < 324) {
                const int hy = y0 - 1 + prj[j];
                const int hx = x0 - 1 + pcj[j];
                const bool valid = (hy >= 0) && (hy < NH_) && (hx >= 0) && (hx < NW_);
                #pragma unroll
                for (int cb = 0; cb < 4; ++cb) {
                    f32x4 al = *reinterpret_cast<const f32x4*>(aff + cb * 16 + lg * 4);
                    f32x4 be = *reinterpret_cast<const f32x4*>(aff + 64 + cb * 16 + lg * 4);
                    bf16x4 pk;
                    #pragma unroll
                    for (int r = 0; r < 4; ++r) {
                        float zv = acc1[j][cb][r] * al[r] + be[r];
                        float hv = zv > 0.f ? zv : apv * zv;
                        pk[r] = valid ? (bf16)hv : (bf16)0.f;
                    }
                    *reinterpret_cast<bf16x4*>(sx + lds_off(p, cb * 2 + (lg >> 1)) + ((lg & 1) << 3)) = pk;
                }
            }
        }
    }
    __syncthreads();                             // h tile visible to all

    // ---- phase 4: conv2 MFMAs (M = pixels, N = co)
    f32x4 acc2[4][4];
    #pragma unroll
    for (int a = 0; a < 4; ++a)
        #pragma unroll
        for (int b = 0; b < 4; ++b) acc2[a][b] = f32x4{0.f, 0.f, 0.f, 0.f};

    const bf16x8* wv2 = reinterpret_cast<const bf16x8*>(wp2);
    #pragma unroll
    for (int ky = 0; ky < 3; ++ky)
    #pragma unroll
    for (int kx = 0; kx < 3; ++kx)
    #pragma unroll
    for (int kb = 0; kb < 2; ++kb) {
        const int tap = ky * 3 + kx;
        bf16x8 wf[4];
        #pragma unroll
        for (int cb = 0; cb < 4; ++cb)
            wf[cb] = wv2[(((tap * 2 + kb) * 4 + cb) << 6) + l];
        #pragma unroll
        for (int pr = 0; pr < 4; ++pr) {
            int p = (w * 4 + pr + ky) * 18 + (l15 + kx);
            bf16x8 xf = *reinterpret_cast<const bf16x8*>(sx + lds_off(p, kb * 4 + lg));
            #pragma unroll
            for (int cb = 0; cb < 4; ++cb)
                acc2[pr][cb] = __builtin_amdgcn_mfma_f32_16x16x32_bf16(xf, wf[cb], acc2[pr][cb], 0, 0, 0);
        }
    }

    // ---- phase 5: BN2 + x + bilinear(Haar edge from GLOBAL f32 x), f32x4
    // stores (NCHW). Tap (gry,grx) clamped to [0,127]^2: clamped duplicate
    // taps reproduce jax's bilinear boundary semantics exactly. Tap source
    // lines are the block's own staged halo rows -> L2/L3-hot.
    #pragma unroll
    for (int cb = 0; cb < 4; ++cb) {
        const int co = cb * 16 + l15;
        const float* xs0 = x + ((size_t)bb * NC_ + co) * HP_;
        float et[4][4];
        #pragma unroll
        for (int r = 0; r < 4; ++r) {
            int gry = (y0 >> 1) - 1 + 2 * w + r;
            gry = gry < 0 ? 0 : (gry > 127 ? 127 : gry);
            const float* row0 = xs0 + (size_t)(2 * gry) * NW_;
            #pragma unroll
            for (int c = 0; c < 4; ++c) {
                int grx = (x0 >> 1) - 1 + 2 * lg + c;
                grx = grx < 0 ? 0 : (grx > 127 ? 127 : grx);
                float2 A = *reinterpret_cast<const float2*>(row0 + 2 * grx);
                float2 B = *reinterpret_cast<const float2*>(row0 + NW_ + 2 * grx);
                et[r][c] = (3.f * A.x - A.y - B.x - B.y) * 0.5f;
            }
        }
        const float al = aff[128 + co];
        const float bt = aff[192 + co];
        #pragma unroll
        for (int pr = 0; pr < 4; ++pr) {
            const int Y = y0 + w * 4 + pr;
            const int Xb = x0 + lg * 4;
            const int ry0 = (pr == 0) ? 0 : (pr == 3 ? 2 : 1);
            const float wyl = (pr & 1) ? 0.75f : 0.25f;
            f32x4 xq = *reinterpret_cast<const f32x4*>(xs0 + Y * NW_ + Xb);
            f32x4 o;
            #pragma unroll
            for (int rr = 0; rr < 4; ++rr) {
                const int rx0 = (rr == 0) ? 0 : (rr == 3 ? 2 : 1);
                const float wxl = (rr & 1) ? 0.75f : 0.25f;
                float e0 = wxl * et[ry0][rx0]     + (1.f - wxl) * et[ry0][rx0 + 1];
                float e1 = wxl * et[ry0 + 1][rx0] + (1.f - wxl) * et[ry0 + 1][rx0 + 1];
                float e  = wyl * e0 + (1.f - wyl) * e1;
                o[rr] = acc2[pr][cb][rr] * al + bt + xq[rr] + e;
            }
            float* os = out + ((size_t)bb * NC_ + co) * HP_ + Y * NW_ + Xb;
            *reinterpret_cast<f32x4*>(os) = o;
        }
    }
}

// ---------------------------------------------------------------------------
extern "C" void kernel_launch(void* const* d_in, const int* in_sizes, int n_in,
                              void* d_out, int out_size, void* d_ws, size_t ws_size,
                              hipStream_t stream)
{
    const float* x   = (const float*)d_in[0];
    const float* w1  = (const float*)d_in[1];
    const float* b1  = (const float*)d_in[2];
    const float* g1  = (const float*)d_in[3];
    const float* be1 = (const float*)d_in[4];
    const float* m1  = (const float*)d_in[5];
    const float* v1  = (const float*)d_in[6];
    const float* ap  = (const float*)d_in[7];
    const float* w2  = (const float*)d_in[8];
    const float* b2  = (const float*)d_in[9];
    const float* g2  = (const float*)d_in[10];
    const float* be2 = (const float*)d_in[11];
    const float* m2  = (const float*)d_in[12];
    const float* v2  = (const float*)d_in[13];

    char* ws = (char*)d_ws;
    bf16*  wp1  = (bf16*)(ws + OFF_W1);
    bf16*  wp2  = (bf16*)(ws + OFF_W2);
    float* aff  = (float*)(ws + OFF_AFF);
    float* outp = (float*)d_out;

    k_pack<<<dim3(290), dim3(256), 0, stream>>>(w1, w2, b1, g1, be1, m1, v1,
                                                b2, g2, be2, m2, v2, wp1, wp2, aff);
    k_fused<<<dim3(2048), dim3(256), 0, stream>>>(x, wp1, wp2, aff, ap, outp);
}

// Round 10
// 181.943 us; speedup vs baseline: 1.7970x; 1.3818x over previous
//
#include <hip/hip_runtime.h>
#include <cstdint>
#include <cstddef>

typedef __bf16 bf16;
typedef __bf16 bf16x8 __attribute__((ext_vector_type(8)));
typedef __bf16 bf16x4 __attribute__((ext_vector_type(4)));
typedef float  f32x4  __attribute__((ext_vector_type(4)));

#define C_EPS 1e-5f
#define NC_ 64
#define NH_ 256
#define NW_ 256
#define HP_ (NH_*NW_)

// workspace layout (bytes)
#define OFF_W1   0ull
#define OFF_W2   73728ull
#define OFF_AFF  147456ull

// swizzled LDS byte offset for [pixel p][ci] bf16 tile (128 B per pixel row),
// 16-B-granule XOR swizzle: pixel stride 128 B == 32 banks -> must swizzle.
__device__ __forceinline__ int lds_off(int p, int cib) {
    return p * 128 + (((cib) ^ (p & 7)) << 4);
}

// ---------------------------------------------------------------------------
// pack weights into MFMA B-frag order + BN affine fold
// packed index u = (((tap*2+kb)*4+nb)*64 + lane)*8 + j
//   lane holds w[co = nb*16 + (lane&15)][ci = kb*32 + (lane>>4)*8 + j][tap]
__global__ void k_pack(const float* __restrict__ w1, const float* __restrict__ w2,
                       const float* __restrict__ b1, const float* __restrict__ g1,
                       const float* __restrict__ be1, const float* __restrict__ m1,
                       const float* __restrict__ v1,
                       const float* __restrict__ b2, const float* __restrict__ g2,
                       const float* __restrict__ be2, const float* __restrict__ m2,
                       const float* __restrict__ v2,
                       bf16* __restrict__ wp1, bf16* __restrict__ wp2,
                       float* __restrict__ aff)
{
    int idx = blockIdx.x * 256 + threadIdx.x;
    if (idx < 2 * 36864) {
        int conv = idx / 36864;
        int u = idx - conv * 36864;
        int j  = u & 7;
        int l  = (u >> 3) & 63;
        int nb = (u >> 9) & 3;
        int kb = (u >> 11) & 1;
        int t  = u >> 12;                  // 0..8
        int co = nb * 16 + (l & 15);
        int ci = kb * 32 + ((l >> 4) << 3) + j;
        const float* w = conv ? w2 : w1;
        float val = w[(co * 64 + ci) * 9 + t];
        (conv ? wp2 : wp1)[u] = (bf16)val;
    } else {
        int c = idx - 2 * 36864;
        if (c < 64) {
            float s = g1[c] / sqrtf(v1[c] + C_EPS);
            aff[c]      = s;
            aff[64 + c] = b1[c] * s + (be1[c] - m1[c] * s);
        } else if (c < 128) {
            int cc = c - 64;
            float s = g2[cc] / sqrtf(v2[cc] + C_EPS);
            aff[128 + cc] = s;
            aff[192 + cc] = b2[cc] * s + (be2[cc] - m2[cc] * s);
        }
    }
}

// ---------------------------------------------------------------------------
// Fully fused, LDS-aliased for 3 blocks/CU:
//   sx  [0, 51200)      : x 20x20 halo; later h 18x18 occupies only [0,41472)
//   seA [41472, 51200)  : se px 0..75  — OVERLAYS x px 324..399 (x rows >=16.2)
//   seB [51200, 54272)  : se px 76..99 — extra 3072 B
// Hazard-free ordering (byte ranges checked):
//   stage x -> bar -> conv1 MFMA (reads all x) + se px76..99 (reads x rows
//   14..19, writes seB only) -> bar -> se px0..75 (reads x rows <=15 =
//   px<=319, writes seA = x px>=324; disjoint) -> bar -> h write px0..323
//   (zero outside image = conv2 SAME padding) -> bar -> conv2 -> epilogue.
// Round-9 NaN root cause: seB phase covered hp 80..99 only; hp 76..79 were
// read in the epilogue but never written (uninitialized LDS). Now 76..99.
// Keep __launch_bounds__(256,2): (256,3) forced 84-VGPR regalloc + ~280 MB
// scratch spill (round-6 PMC). With ~130 VGPR occupancy is LDS-limited at 3.
__global__ __launch_bounds__(256, 2)
void k_fused(const float* __restrict__ x, const bf16* __restrict__ wp1,
             const bf16* __restrict__ wp2, const float* __restrict__ aff,
             const float* __restrict__ aprelu, float* __restrict__ out)
{
    __shared__ uint4 smem[3392];                 // 54272 B
    char* sx  = reinterpret_cast<char*>(smem);
    char* seA = reinterpret_cast<char*>(smem) + 41472;
    char* seB = reinterpret_cast<char*>(smem) + 51200;
    const int t = threadIdx.x;

    // XCD-bijective swizzle (2048 blocks, 8 XCDs): each XCD owns one image
    const int bid = blockIdx.x;
    const int logical = (bid & 7) * 256 + (bid >> 3);
    const int x0 = (logical & 15) * 16;
    const int y0 = ((logical >> 4) & 15) * 16;
    const int bb = logical >> 8;
    const float* xb = x + (size_t)bb * NC_ * HP_;

    // ---- phase 1: stage x 20x20 halo (origin y0-2, x0-2) x 64 ci as bf16
    for (int i = 0; i < 25; ++i) {
        int item = i * 256 + t;                  // 6400 = 16 ci4 * 400 px
        int ci4 = item / 400;
        int p   = item - ci4 * 400;
        int r = p / 20, c = p - r * 20;
        int yy = y0 - 2 + r, xx = x0 - 2 + c;
        float v0 = 0.f, v1 = 0.f, v2 = 0.f, v3 = 0.f;
        if (yy >= 0 && yy < NH_ && xx >= 0 && xx < NW_) {
            const float* s = xb + (size_t)(ci4 * 4) * HP_ + yy * NW_ + xx;
            v0 = s[0]; v1 = s[HP_]; v2 = s[2 * HP_]; v3 = s[3 * HP_];
        }
        bf16x4 pk = { (bf16)v0, (bf16)v1, (bf16)v2, (bf16)v3 };
        *reinterpret_cast<bf16x4*>(sx + lds_off(p, ci4 >> 1) + ((ci4 & 1) << 3)) = pk;
    }
    __syncthreads();

    const int w = t >> 6, l = t & 63;
    const int l15 = l & 15, lg = l >> 4;

    // ---- phase 2: conv1 MFMAs -> 18x18 h in registers
    f32x4 acc1[6][4];
    #pragma unroll
    for (int j = 0; j < 6; ++j)
        #pragma unroll
        for (int cb = 0; cb < 4; ++cb) acc1[j][cb] = f32x4{0.f, 0.f, 0.f, 0.f};

    int prj[6], pcj[6];
    #pragma unroll
    for (int j = 0; j < 6; ++j) {
        int g = w + 4 * j;
        int p = g * 16 + l15; if (p > 323) p = 323;   // addr-safe clamp
        prj[j] = p / 18; pcj[j] = p - prj[j] * 18;
    }

    const bf16x8* wv1 = reinterpret_cast<const bf16x8*>(wp1);
    #pragma unroll
    for (int ky = 0; ky < 3; ++ky)
    #pragma unroll
    for (int kx = 0; kx < 3; ++kx)
    #pragma unroll
    for (int kb = 0; kb < 2; ++kb) {
        const int tap = ky * 3 + kx;
        bf16x8 wf[4];
        #pragma unroll
        for (int cb = 0; cb < 4; ++cb)
            wf[cb] = wv1[(((tap * 2 + kb) * 4 + cb) << 6) + l];
        #pragma unroll
        for (int j = 0; j < 6; ++j) {
            if (w + 4 * j > 20) continue;        // wave-uniform guard
            bf16x8 xf = *reinterpret_cast<const bf16x8*>(
                sx + lds_off((prj[j] + ky) * 20 + pcj[j] + kx, kb * 4 + lg));
            #pragma unroll
            for (int cb = 0; cb < 4; ++cb)
                acc1[j][cb] = __builtin_amdgcn_mfma_f32_16x16x32_bf16(wf[cb], xf, acc1[j][cb], 0, 0, 0);
        }
    }

    // ---- phase 2b: se px 76..99 (24 px x 64 ci = 1536 units): reads x rows
    // 14..19 (original x, nothing overwritten yet), writes seB (outside the
    // x region) — safe alongside conv1's x reads in this barrier epoch.
    #pragma unroll
    for (int i = 0; i < 6; ++i) {
        int unit = i * 256 + t;                  // 1536 = 24 hp * 64 ci
        int ci = unit & 63;
        int hp = 76 + (unit >> 6);               // 76..99
        int ry = hp / 10, rx = hp - ry * 10;
        int ryg = (y0 >> 1) - 1 + ry; ryg = ryg < 0 ? 0 : (ryg > 127 ? 127 : ryg);
        int rxg = (x0 >> 1) - 1 + rx; rxg = rxg < 0 ? 0 : (rxg > 127 ? 127 : rxg);
        int pA = (2 * ryg - y0 + 2) * 20 + (2 * rxg - x0 + 2);
        int cib = ci >> 3, cio = (ci & 7) << 1;
        float a  = (float)*reinterpret_cast<const bf16*>(sx + lds_off(pA,      cib) + cio);
        float b_ = (float)*reinterpret_cast<const bf16*>(sx + lds_off(pA + 1,  cib) + cio);
        float c_ = (float)*reinterpret_cast<const bf16*>(sx + lds_off(pA + 20, cib) + cio);
        float d_ = (float)*reinterpret_cast<const bf16*>(sx + lds_off(pA + 21, cib) + cio);
        *reinterpret_cast<bf16*>(seB + lds_off(hp - 76, cib) + cio) =
            (bf16)((3.f * a - b_ - c_ - d_) * 0.5f);
    }
    __syncthreads();                             // all conv1/se-high x reads done

    // ---- phase 2c: se px 0..75 (grid rows 0..7): reads x rows <=15
    // (bytes of px <=319), writes seA = x px 324..399 — disjoint byte ranges.
    #pragma unroll
    for (int i = 0; i < 19; ++i) {
        int unit = i * 256 + t;                  // 4864 = 76 hp * 64 ci
        int ci = unit & 63;
        int hp = unit >> 6;                      // 0..75
        int ry = hp / 10, rx = hp - ry * 10;
        int ryg = (y0 >> 1) - 1 + ry; ryg = ryg < 0 ? 0 : (ryg > 127 ? 127 : ryg);
        int rxg = (x0 >> 1) - 1 + rx; rxg = rxg < 0 ? 0 : (rxg > 127 ? 127 : rxg);
        int pA = (2 * ryg - y0 + 2) * 20 + (2 * rxg - x0 + 2);
        int cib = ci >> 3, cio = (ci & 7) << 1;
        float a  = (float)*reinterpret_cast<const bf16*>(sx + lds_off(pA,      cib) + cio);
        float b_ = (float)*reinterpret_cast<const bf16*>(sx + lds_off(pA + 1,  cib) + cio);
        float c_ = (float)*reinterpret_cast<const bf16*>(sx + lds_off(pA + 20, cib) + cio);
        float d_ = (float)*reinterpret_cast<const bf16*>(sx + lds_off(pA + 21, cib) + cio);
        *reinterpret_cast<bf16*>(seA + lds_off(hp, cib) + cio) =
            (bf16)((3.f * a - b_ - c_ - d_) * 0.5f);
    }
    __syncthreads();                             // se-low x reads done

    // ---- phase 3: BN1 + PReLU, write h over x px 0..323 (bytes [0,41472)).
    // h pixels whose GLOBAL coords fall outside the image must be ZERO
    // (conv2's SAME padding pads h with zeros) — not conv1-of-padded-x.
    {
        const float apv = aprelu[0];
        #pragma unroll
        for (int j = 0; j < 6; ++j) {
            int g = w + 4 * j;
            if (g > 20) continue;
            int p = g * 16 + l15;
            if (p < 324) {
                const int hy = y0 - 1 + prj[j];
                const int hx = x0 - 1 + pcj[j];
                const bool valid = (hy >= 0) && (hy < NH_) && (hx >= 0) && (hx < NW_);
                #pragma unroll
                for (int cb = 0; cb < 4; ++cb) {
                    f32x4 al = *reinterpret_cast<const f32x4*>(aff + cb * 16 + lg * 4);
                    f32x4 be = *reinterpret_cast<const f32x4*>(aff + 64 + cb * 16 + lg * 4);
                    bf16x4 pk;
                    #pragma unroll
                    for (int r = 0; r < 4; ++r) {
                        float zv = acc1[j][cb][r] * al[r] + be[r];
                        float hv = zv > 0.f ? zv : apv * zv;
                        pk[r] = valid ? (bf16)hv : (bf16)0.f;
                    }
                    *reinterpret_cast<bf16x4*>(sx + lds_off(p, cb * 2 + (lg >> 1)) + ((lg & 1) << 3)) = pk;
                }
            }
        }
    }
    __syncthreads();                             // h tile visible to all

    // ---- phase 4: conv2 MFMAs (M = pixels, N = co)
    f32x4 acc2[4][4];
    #pragma unroll
    for (int a = 0; a < 4; ++a)
        #pragma unroll
        for (int b = 0; b < 4; ++b) acc2[a][b] = f32x4{0.f, 0.f, 0.f, 0.f};

    const bf16x8* wv2 = reinterpret_cast<const bf16x8*>(wp2);
    #pragma unroll
    for (int ky = 0; ky < 3; ++ky)
    #pragma unroll
    for (int kx = 0; kx < 3; ++kx)
    #pragma unroll
    for (int kb = 0; kb < 2; ++kb) {
        const int tap = ky * 3 + kx;
        bf16x8 wf[4];
        #pragma unroll
        for (int cb = 0; cb < 4; ++cb)
            wf[cb] = wv2[(((tap * 2 + kb) * 4 + cb) << 6) + l];
        #pragma unroll
        for (int pr = 0; pr < 4; ++pr) {
            int p = (w * 4 + pr + ky) * 18 + (l15 + kx);
            bf16x8 xf = *reinterpret_cast<const bf16x8*>(sx + lds_off(p, kb * 4 + lg));
            #pragma unroll
            for (int cb = 0; cb < 4; ++cb)
                acc2[pr][cb] = __builtin_amdgcn_mfma_f32_16x16x32_bf16(xf, wf[cb], acc2[pr][cb], 0, 0, 0);
        }
    }

    // ---- phase 5: BN2 + x (global, L2-hot) + bilinear(se from seA/seB),
    // f32x4 stores (NCHW). Same math as the round-4 passing kernel.
    #pragma unroll
    for (int cb = 0; cb < 4; ++cb) {
        const int co = cb * 16 + l15;
        const int cib2 = co >> 3;
        const int cio = (co & 7) << 1;
        float et[4][4];
        #pragma unroll
        for (int r = 0; r < 4; ++r)
            #pragma unroll
            for (int c = 0; c < 4; ++c) {
                int ep = (2 * w + r) * 10 + (2 * lg + c);
                const char* sep = (ep < 76) ? (seA + lds_off(ep, cib2))
                                            : (seB + lds_off(ep - 76, cib2));
                et[r][c] = (float)*reinterpret_cast<const bf16*>(sep + cio);
            }
        const float al = aff[128 + co];
        const float bt = aff[192 + co];
        const float* xs0 = x + ((size_t)bb * NC_ + co) * HP_;
        #pragma unroll
        for (int pr = 0; pr < 4; ++pr) {
            const int Y = y0 + w * 4 + pr;
            const int Xb = x0 + lg * 4;
            const int ry0 = (pr == 0) ? 0 : (pr == 3 ? 2 : 1);
            const float wyl = (pr & 1) ? 0.75f : 0.25f;
            f32x4 xq = *reinterpret_cast<const f32x4*>(xs0 + Y * NW_ + Xb);
            f32x4 o;
            #pragma unroll
            for (int rr = 0; rr < 4; ++rr) {
                const int rx0 = (rr == 0) ? 0 : (rr == 3 ? 2 : 1);
                const float wxl = (rr & 1) ? 0.75f : 0.25f;
                float e0 = wxl * et[ry0][rx0]     + (1.f - wxl) * et[ry0][rx0 + 1];
                float e1 = wxl * et[ry0 + 1][rx0] + (1.f - wxl) * et[ry0 + 1][rx0 + 1];
                float e  = wyl * e0 + (1.f - wyl) * e1;
                o[rr] = acc2[pr][cb][rr] * al + bt + xq[rr] + e;
            }
            float* os = out + ((size_t)bb * NC_ + co) * HP_ + Y * NW_ + Xb;
            *reinterpret_cast<f32x4*>(os) = o;
        }
    }
}

// ---------------------------------------------------------------------------
extern "C" void kernel_launch(void* const* d_in, const int* in_sizes, int n_in,
                              void* d_out, int out_size, void* d_ws, size_t ws_size,
                              hipStream_t stream)
{
    const float* x   = (const float*)d_in[0];
    const float* w1  = (const float*)d_in[1];
    const float* b1  = (const float*)d_in[2];
    const float* g1  = (const float*)d_in[3];
    const float* be1 = (const float*)d_in[4];
    const float* m1  = (const float*)d_in[5];
    const float* v1  = (const float*)d_in[6];
    const float* ap  = (const float*)d_in[7];
    const float* w2  = (const float*)d_in[8];
    const float* b2  = (const float*)d_in[9];
    const float* g2  = (const float*)d_in[10];
    const float* be2 = (const float*)d_in[11];
    const float* m2  = (const float*)d_in[12];
    const float* v2  = (const float*)d_in[13];

    char* ws = (char*)d_ws;
    bf16*  wp1  = (bf16*)(ws + OFF_W1);
    bf16*  wp2  = (bf16*)(ws + OFF_W2);
    float* aff  = (float*)(ws + OFF_AFF);
    float* outp = (float*)d_out;

    k_pack<<<dim3(290), dim3(256), 0, stream>>>(w1, w2, b1, g1, be1, m1, v1,
                                                b2, g2, be2, m2, v2, wp1, wp2, aff);
    k_fused<<<dim3(2048), dim3(256), 0, stream>>>(x, wp1, wp2, aff, ap, outp);
}